// Round 3
// baseline (148.922 us; speedup 1.0000x reference)
//
#include <hip/hip_runtime.h>

#define W 512
#define H 512
#define PLANE (W * H)            // 262144
#define NBATCH 32                // 4*8
#define NPTS (NBATCH * PLANE)    // 8388608 spatial points per channel
#define NBLK 4096                // loss-kernel grid size (16384 waves, 1 row each)

static constexpr float DT_INV = 100.0f;   // 1/DT
static constexpr float NU_C   = 0.001f;
// DX = 1.0 -> grad scale 0.5, laplacian scale 1.0

// One wave = one full row (64 lanes x 8 pts = 512 = W). X-neighbors via
// __shfl lane ring (512-periodic row maps exactly onto the 64-lane ring).
// All loads are coalesced float4; 16 B/pt = the unique-data minimum.
__global__ __launch_bounds__(256) void ns_loss_v3(
    const float* __restrict__ u_pred,
    const float* __restrict__ u_prev,
    float* __restrict__ partial)
{
    const int lane = threadIdx.x & 63;
    const int wv   = threadIdx.x >> 6;
    const int gw   = (blockIdx.x << 2) | wv;   // global wave id: 0..16383
    const int y    = gw & 511;
    const int b    = gw >> 9;                  // 0..31

    const float* u0 = u_pred + (size_t)b * (2 * PLANE);
    const float* v0 = u0 + PLANE;
    const float* q0 = u_prev + (size_t)b * (2 * PLANE);
    const float* q1 = q0 + PLANE;

    const int rowc = y * W;
    const int rowm = ((y - 1) & 511) * W;
    const int rowp = ((y + 1) & 511) * W;
    const int x0   = lane << 3;                // 8 consecutive x per lane

    // 16 coalesced float4 loads (all independent -> high MLP)
    const float4 ucl = *(const float4*)(u0 + rowc + x0);
    const float4 uch = *(const float4*)(u0 + rowc + x0 + 4);
    const float4 uml = *(const float4*)(u0 + rowm + x0);
    const float4 umh = *(const float4*)(u0 + rowm + x0 + 4);
    const float4 upl = *(const float4*)(u0 + rowp + x0);
    const float4 uph = *(const float4*)(u0 + rowp + x0 + 4);
    const float4 vcl = *(const float4*)(v0 + rowc + x0);
    const float4 vch = *(const float4*)(v0 + rowc + x0 + 4);
    const float4 vml = *(const float4*)(v0 + rowm + x0);
    const float4 vmh = *(const float4*)(v0 + rowm + x0 + 4);
    const float4 vpl = *(const float4*)(v0 + rowp + x0);
    const float4 vph = *(const float4*)(v0 + rowp + x0 + 4);
    const float4 pul = *(const float4*)(q0 + rowc + x0);
    const float4 puh = *(const float4*)(q0 + rowc + x0 + 4);
    const float4 pvl = *(const float4*)(q1 + rowc + x0);
    const float4 pvh = *(const float4*)(q1 + rowc + x0 + 4);

    // x-neighbors across the lane ring (wraps match the periodic row)
    const int lm = (lane + 63) & 63;
    const int lp = (lane + 1) & 63;
    const float uLm1 = __shfl(uch.w, lm);   // u[x0-1] from left lane
    const float uRp1 = __shfl(ucl.x, lp);   // u[x0+8] from right lane
    const float vLm1 = __shfl(vch.w, lm);
    const float vRp1 = __shfl(vcl.x, lp);

    const float ua[10] = {uLm1, ucl.x, ucl.y, ucl.z, ucl.w,
                          uch.x, uch.y, uch.z, uch.w, uRp1};
    const float va[10] = {vLm1, vcl.x, vcl.y, vcl.z, vcl.w,
                          vch.x, vch.y, vch.z, vch.w, vRp1};
    const float umA[8] = {uml.x, uml.y, uml.z, uml.w, umh.x, umh.y, umh.z, umh.w};
    const float upA[8] = {upl.x, upl.y, upl.z, upl.w, uph.x, uph.y, uph.z, uph.w};
    const float vmA[8] = {vml.x, vml.y, vml.z, vml.w, vmh.x, vmh.y, vmh.z, vmh.w};
    const float vpA[8] = {vpl.x, vpl.y, vpl.z, vpl.w, vph.x, vph.y, vph.z, vph.w};
    const float puA[8] = {pul.x, pul.y, pul.z, pul.w, puh.x, puh.y, puh.z, puh.w};
    const float pvA[8] = {pvl.x, pvl.y, pvl.z, pvl.w, pvh.x, pvh.y, pvh.z, pvh.w};

    float s_pde = 0.0f, s_div = 0.0f;
#pragma unroll
    for (int j = 0; j < 8; ++j) {
        const float u   = ua[j + 1];
        const float v   = va[j + 1];
        const float u_x = (ua[j + 2] - ua[j]) * 0.5f;
        const float v_x = (va[j + 2] - va[j]) * 0.5f;
        const float u_y = (upA[j] - umA[j]) * 0.5f;
        const float v_y = (vpA[j] - vmA[j]) * 0.5f;
        const float lap_u = upA[j] + umA[j] + ua[j + 2] + ua[j] - 4.0f * u;
        const float lap_v = vpA[j] + vmA[j] + va[j + 2] + va[j] - 4.0f * v;
        const float rx = (u - puA[j]) * DT_INV + u * u_x + v * u_y - NU_C * lap_u;
        const float ry = (v - pvA[j]) * DT_INV + u * v_x + v * v_y - NU_C * lap_v;
        const float dv = u_x + v_y;
        s_pde += rx * rx + ry * ry;
        s_div += dv * dv;
    }

    // wave reduction
#pragma unroll
    for (int off = 32; off > 0; off >>= 1) {
        s_pde += __shfl_down(s_pde, off);
        s_div += __shfl_down(s_div, off);
    }

    __shared__ float sp[4], sd[4];
    if (lane == 0) { sp[wv] = s_pde; sd[wv] = s_div; }
    __syncthreads();
    if (threadIdx.x == 0) {
        partial[blockIdx.x]        = sp[0] + sp[1] + sp[2] + sp[3];
        partial[NBLK + blockIdx.x] = sd[0] + sd[1] + sd[2] + sd[3];
    }
}

__global__ __launch_bounds__(256) void ns_reduce(
    const float* __restrict__ partial,
    float* __restrict__ out)
{
    double sp = 0.0, sd = 0.0;
    for (int i = threadIdx.x; i < NBLK; i += 256) {
        sp += (double)partial[i];
        sd += (double)partial[NBLK + i];
    }
#pragma unroll
    for (int off = 32; off > 0; off >>= 1) {
        sp += __shfl_down(sp, off);
        sd += __shfl_down(sd, off);
    }
    __shared__ double ssp[4], ssd[4];
    const int lane = threadIdx.x & 63;
    const int wv   = threadIdx.x >> 6;
    if (lane == 0) { ssp[wv] = sp; ssd[wv] = sd; }
    __syncthreads();
    if (threadIdx.x == 0) {
        const double tp = ssp[0] + ssp[1] + ssp[2] + ssp[3];
        const double td = ssd[0] + ssd[1] + ssd[2] + ssd[3];
        const double inv = 1.0 / (double)NPTS;
        const double pde = tp * inv;
        const double dvl = td * inv;
        out[0] = (float)(pde + 0.1 * dvl);
        out[1] = (float)pde;
        out[2] = (float)dvl;
    }
}

extern "C" void kernel_launch(void* const* d_in, const int* in_sizes, int n_in,
                              void* d_out, int out_size, void* d_ws, size_t ws_size,
                              hipStream_t stream) {
    const float* u_pred = (const float*)d_in[0];
    const float* u_prev = (const float*)d_in[1];
    float* out = (float*)d_out;
    float* partial = (float*)d_ws;   // 2*NBLK floats = 32 KB

    ns_loss_v3<<<NBLK, 256, 0, stream>>>(u_pred, u_prev, partial);
    ns_reduce<<<1, 256, 0, stream>>>(partial, out);
}

// Round 4
// 146.905 us; speedup vs baseline: 1.0137x; 1.0137x over previous
//
#include <hip/hip_runtime.h>

#define W 512
#define H 512
#define PLANE (W * H)            // 262144
#define NBATCH 32                // 4*8
#define NPTS (NBATCH * PLANE)    // 8388608 spatial points per channel
#define NBLK 2048                // 8192 waves, 2 rows each = 16384 row-tasks

static constexpr float DT_INV = 100.0f;   // 1/DT
static constexpr float NU_C   = 0.001f;
// DX = 1.0 -> grad scale 0.5, laplacian scale 1.0

// Compute one row's loss contribution from pre-loaded registers.
// ucl/uch: u row y (lo/hi half per lane); uml/umh: row y-1; upl/uph: row y+1;
// same for v; pul/puh, pvl/pvh: u_prev/v_prev row y.
__device__ __forceinline__ void row_loss(
    const float4 ucl, const float4 uch, const float4 uml, const float4 umh,
    const float4 upl, const float4 uph, const float4 vcl, const float4 vch,
    const float4 vml, const float4 vmh, const float4 vpl, const float4 vph,
    const float4 pul, const float4 puh, const float4 pvl, const float4 pvh,
    const int lm, const int lp, float& s_pde, float& s_div)
{
    // x-neighbors across the 64-lane ring (512-periodic row maps exactly)
    const float uLm1 = __shfl(uch.w, lm);
    const float uRp1 = __shfl(ucl.x, lp);
    const float vLm1 = __shfl(vch.w, lm);
    const float vRp1 = __shfl(vcl.x, lp);

    const float ua[10] = {uLm1, ucl.x, ucl.y, ucl.z, ucl.w,
                          uch.x, uch.y, uch.z, uch.w, uRp1};
    const float va[10] = {vLm1, vcl.x, vcl.y, vcl.z, vcl.w,
                          vch.x, vch.y, vch.z, vch.w, vRp1};
    const float umA[8] = {uml.x, uml.y, uml.z, uml.w, umh.x, umh.y, umh.z, umh.w};
    const float upA[8] = {upl.x, upl.y, upl.z, upl.w, uph.x, uph.y, uph.z, uph.w};
    const float vmA[8] = {vml.x, vml.y, vml.z, vml.w, vmh.x, vmh.y, vmh.z, vmh.w};
    const float vpA[8] = {vpl.x, vpl.y, vpl.z, vpl.w, vph.x, vph.y, vph.z, vph.w};
    const float puA[8] = {pul.x, pul.y, pul.z, pul.w, puh.x, puh.y, puh.z, puh.w};
    const float pvA[8] = {pvl.x, pvl.y, pvl.z, pvl.w, pvh.x, pvh.y, pvh.z, pvh.w};

#pragma unroll
    for (int j = 0; j < 8; ++j) {
        const float u   = ua[j + 1];
        const float v   = va[j + 1];
        const float u_x = (ua[j + 2] - ua[j]) * 0.5f;
        const float v_x = (va[j + 2] - va[j]) * 0.5f;
        const float u_y = (upA[j] - umA[j]) * 0.5f;
        const float v_y = (vpA[j] - vmA[j]) * 0.5f;
        const float lap_u = upA[j] + umA[j] + ua[j + 2] + ua[j] - 4.0f * u;
        const float lap_v = vpA[j] + vmA[j] + va[j + 2] + va[j] - 4.0f * v;
        const float rx = (u - puA[j]) * DT_INV + u * u_x + v * u_y - NU_C * lap_u;
        const float ry = (v - pvA[j]) * DT_INV + u * v_x + v * v_y - NU_C * lap_v;
        const float dv = u_x + v_y;
        s_pde += rx * rx + ry * ry;
        s_div += dv * dv;
    }
}

// One wave = two full rows (far apart). All 32 float4 loads issued up-front
// so each wave has 32 independent vmem ops in flight -> latency hidden
// in-wave. __launch_bounds__(256,2) lifts the VGPR cap to ~256 so the
// compiler can keep them all live.
__global__ __launch_bounds__(256, 2) void ns_loss_v4(
    const float* __restrict__ u_pred,
    const float* __restrict__ u_prev,
    float* __restrict__ partial)
{
    const int lane = threadIdx.x & 63;
    const int wv   = threadIdx.x >> 6;
    const int gw   = (blockIdx.x << 2) | wv;   // 0..8191

    const int x0 = lane << 3;                  // 8 consecutive x per lane
    const int lm = (lane + 63) & 63;
    const int lp = (lane + 1) & 63;

    // ---- task A: row-task gw ----
    const int tA = gw;
    const int yA = tA & 511;
    const int bA = tA >> 9;
    const float* uA = u_pred + (size_t)bA * (2 * PLANE);
    const float* vA = uA + PLANE;
    const float* qA0 = u_prev + (size_t)bA * (2 * PLANE);
    const float* qA1 = qA0 + PLANE;
    const int rcA = yA * W;
    const int rmA = ((yA - 1) & 511) * W;
    const int rpA = ((yA + 1) & 511) * W;

    // ---- task B: row-task gw + 8192 ----
    const int tB = gw + 8192;
    const int yB = tB & 511;
    const int bB = tB >> 9;
    const float* uB = u_pred + (size_t)bB * (2 * PLANE);
    const float* vB = uB + PLANE;
    const float* qB0 = u_prev + (size_t)bB * (2 * PLANE);
    const float* qB1 = qB0 + PLANE;
    const int rcB = yB * W;
    const int rmB = ((yB - 1) & 511) * W;
    const int rpB = ((yB + 1) & 511) * W;

    // ---- all 32 loads issued before any consumption ----
    const float4 AucL = *(const float4*)(uA + rcA + x0);
    const float4 AucH = *(const float4*)(uA + rcA + x0 + 4);
    const float4 AumL = *(const float4*)(uA + rmA + x0);
    const float4 AumH = *(const float4*)(uA + rmA + x0 + 4);
    const float4 AupL = *(const float4*)(uA + rpA + x0);
    const float4 AupH = *(const float4*)(uA + rpA + x0 + 4);
    const float4 AvcL = *(const float4*)(vA + rcA + x0);
    const float4 AvcH = *(const float4*)(vA + rcA + x0 + 4);
    const float4 AvmL = *(const float4*)(vA + rmA + x0);
    const float4 AvmH = *(const float4*)(vA + rmA + x0 + 4);
    const float4 AvpL = *(const float4*)(vA + rpA + x0);
    const float4 AvpH = *(const float4*)(vA + rpA + x0 + 4);
    const float4 ApuL = *(const float4*)(qA0 + rcA + x0);
    const float4 ApuH = *(const float4*)(qA0 + rcA + x0 + 4);
    const float4 ApvL = *(const float4*)(qA1 + rcA + x0);
    const float4 ApvH = *(const float4*)(qA1 + rcA + x0 + 4);

    const float4 BucL = *(const float4*)(uB + rcB + x0);
    const float4 BucH = *(const float4*)(uB + rcB + x0 + 4);
    const float4 BumL = *(const float4*)(uB + rmB + x0);
    const float4 BumH = *(const float4*)(uB + rmB + x0 + 4);
    const float4 BupL = *(const float4*)(uB + rpB + x0);
    const float4 BupH = *(const float4*)(uB + rpB + x0 + 4);
    const float4 BvcL = *(const float4*)(vB + rcB + x0);
    const float4 BvcH = *(const float4*)(vB + rcB + x0 + 4);
    const float4 BvmL = *(const float4*)(vB + rmB + x0);
    const float4 BvmH = *(const float4*)(vB + rmB + x0 + 4);
    const float4 BvpL = *(const float4*)(vB + rpB + x0);
    const float4 BvpH = *(const float4*)(vB + rpB + x0 + 4);
    const float4 BpuL = *(const float4*)(qB0 + rcB + x0);
    const float4 BpuH = *(const float4*)(qB0 + rcB + x0 + 4);
    const float4 BpvL = *(const float4*)(qB1 + rcB + x0);
    const float4 BpvH = *(const float4*)(qB1 + rcB + x0 + 4);

    float s_pde = 0.0f, s_div = 0.0f;
    row_loss(AucL, AucH, AumL, AumH, AupL, AupH, AvcL, AvcH,
             AvmL, AvmH, AvpL, AvpH, ApuL, ApuH, ApvL, ApvH,
             lm, lp, s_pde, s_div);
    row_loss(BucL, BucH, BumL, BumH, BupL, BupH, BvcL, BvcH,
             BvmL, BvmH, BvpL, BvpH, BpuL, BpuH, BpvL, BpvH,
             lm, lp, s_pde, s_div);

    // wave reduction
#pragma unroll
    for (int off = 32; off > 0; off >>= 1) {
        s_pde += __shfl_down(s_pde, off);
        s_div += __shfl_down(s_div, off);
    }

    __shared__ float sp[4], sd[4];
    if (lane == 0) { sp[wv] = s_pde; sd[wv] = s_div; }
    __syncthreads();
    if (threadIdx.x == 0) {
        partial[blockIdx.x]        = sp[0] + sp[1] + sp[2] + sp[3];
        partial[NBLK + blockIdx.x] = sd[0] + sd[1] + sd[2] + sd[3];
    }
}

__global__ __launch_bounds__(256) void ns_reduce(
    const float* __restrict__ partial,
    float* __restrict__ out)
{
    double sp = 0.0, sd = 0.0;
    for (int i = threadIdx.x; i < NBLK; i += 256) {
        sp += (double)partial[i];
        sd += (double)partial[NBLK + i];
    }
#pragma unroll
    for (int off = 32; off > 0; off >>= 1) {
        sp += __shfl_down(sp, off);
        sd += __shfl_down(sd, off);
    }
    __shared__ double ssp[4], ssd[4];
    const int lane = threadIdx.x & 63;
    const int wv   = threadIdx.x >> 6;
    if (lane == 0) { ssp[wv] = sp; ssd[wv] = sd; }
    __syncthreads();
    if (threadIdx.x == 0) {
        const double tp = ssp[0] + ssp[1] + ssp[2] + ssp[3];
        const double td = ssd[0] + ssd[1] + ssd[2] + ssd[3];
        const double inv = 1.0 / (double)NPTS;
        const double pde = tp * inv;
        const double dvl = td * inv;
        out[0] = (float)(pde + 0.1 * dvl);
        out[1] = (float)pde;
        out[2] = (float)dvl;
    }
}

extern "C" void kernel_launch(void* const* d_in, const int* in_sizes, int n_in,
                              void* d_out, int out_size, void* d_ws, size_t ws_size,
                              hipStream_t stream) {
    const float* u_pred = (const float*)d_in[0];
    const float* u_prev = (const float*)d_in[1];
    float* out = (float*)d_out;
    float* partial = (float*)d_ws;   // 2*NBLK floats = 16 KB

    ns_loss_v4<<<NBLK, 256, 0, stream>>>(u_pred, u_prev, partial);
    ns_reduce<<<1, 256, 0, stream>>>(partial, out);
}

// Round 5
// 146.581 us; speedup vs baseline: 1.0160x; 1.0022x over previous
//
#include <hip/hip_runtime.h>

#define W 512
#define H 512
#define PLANE (W * H)            // 262144
#define NBATCH 32                // 4*8
#define NPTS (NBATCH * PLANE)    // 8388608 spatial points per channel
#define ROWS 8                   // compute rows per block
#define STRIP (ROWS + 2)         // staged rows (with y halo) = 10
#define NBLK 2048                // 32 batches * 64 strips

static constexpr float DT_INV = 100.0f;   // 1/DT
static constexpr float NU_C   = 0.001f;
// DX = 1.0 -> grad scale 0.5, laplacian scale 1.0

// Each block: one batch, 8-row tile. u and v strips (10 rows each, with
// periodic y-halo) staged into LDS via async global_load_lds DMA (16 B/lane,
// 1024 B per wave-instruction, 40 instructions per block). u_prev/v_prev
// center rows stream straight to registers. Stencil computed from LDS.
__global__ __launch_bounds__(256) void ns_loss_v5(
    const float* __restrict__ u_pred,
    const float* __restrict__ u_prev,
    float* __restrict__ partial)
{
    __shared__ float smem[2 * STRIP * W];   // u strip | v strip, 40960 B

    const int t    = threadIdx.x;
    const int lane = t & 63;
    const int wv   = t >> 6;
    const int b     = blockIdx.x >> 6;      // 0..31
    const int strip = blockIdx.x & 63;      // 0..63
    const int y0    = strip << 3;

    const float* u0 = u_pred + (size_t)b * (2 * PLANE);
    const float* v0 = u0 + PLANE;
    const float* q0 = u_prev + (size_t)b * (2 * PLANE);
    const float* q1 = q0 + PLANE;

    // ---- async DMA staging: 40 segments of 1024 B (half-rows) ----
    // segment s: channel = s/20, strip-row r = (s%20)>>1, half h = s&1
#pragma unroll
    for (int k = 0; k < 10; ++k) {
        const int s  = wv * 10 + k;
        const int ch = s / 20;
        const int r  = (s % 20) >> 1;
        const int h  = s & 1;
        const int grow = (y0 - 1 + r) & 511;
        const float* gsrc = (ch ? v0 : u0) + grow * W + h * 256 + lane * 4;
        float* ldst = smem + ch * (STRIP * W) + r * W + h * 256; // wave-uniform base
        __builtin_amdgcn_global_load_lds(
            (const __attribute__((address_space(1))) void*)gsrc,
            (__attribute__((address_space(3))) void*)ldst, 16, 0, 0);
    }

    // ---- stream prev center rows to registers (overlaps with DMA) ----
    const int rr = t >> 5;                // tile row 0..7
    const int cx = (t & 31) << 2;         // base col, lanes spread 4-float quads
    const int yc = y0 + rr;
    const int rowg = yc * W;
    float4 pu[4], pv[4];
#pragma unroll
    for (int g = 0; g < 4; ++g) {
        const int x = cx + (g << 7);
        pu[g] = *(const float4*)(q0 + rowg + x);
        pv[g] = *(const float4*)(q1 + rowg + x);
    }

    __syncthreads();   // drains DMA (vmcnt) + barrier

    // ---- stencil from LDS ----
    const float* us = smem;
    const float* vs = smem + STRIP * W;
    const int rc = rr + 1;                // center row inside strip

    float s_pde = 0.0f, s_div = 0.0f;
#pragma unroll
    for (int g = 0; g < 4; ++g) {
        const int x = cx + (g << 7);
        const float4 uc = *(const float4*)(us + rc * W + x);
        const float4 um = *(const float4*)(us + (rc - 1) * W + x);
        const float4 up = *(const float4*)(us + (rc + 1) * W + x);
        const float4 vc = *(const float4*)(vs + rc * W + x);
        const float4 vm = *(const float4*)(vs + (rc - 1) * W + x);
        const float4 vp = *(const float4*)(vs + (rc + 1) * W + x);
        const float uL = us[rc * W + ((x - 1) & 511)];
        const float uR = us[rc * W + ((x + 4) & 511)];
        const float vL = vs[rc * W + ((x - 1) & 511)];
        const float vR = vs[rc * W + ((x + 4) & 511)];

        const float ua[6]  = {uL, uc.x, uc.y, uc.z, uc.w, uR};
        const float va[6]  = {vL, vc.x, vc.y, vc.z, vc.w, vR};
        const float umA[4] = {um.x, um.y, um.z, um.w};
        const float upA[4] = {up.x, up.y, up.z, up.w};
        const float vmA[4] = {vm.x, vm.y, vm.z, vm.w};
        const float vpA[4] = {vp.x, vp.y, vp.z, vp.w};
        const float puA[4] = {pu[g].x, pu[g].y, pu[g].z, pu[g].w};
        const float pvA[4] = {pv[g].x, pv[g].y, pv[g].z, pv[g].w};

#pragma unroll
        for (int j = 0; j < 4; ++j) {
            const float u   = ua[j + 1];
            const float v   = va[j + 1];
            const float u_x = (ua[j + 2] - ua[j]) * 0.5f;
            const float v_x = (va[j + 2] - va[j]) * 0.5f;
            const float u_y = (upA[j] - umA[j]) * 0.5f;
            const float v_y = (vpA[j] - vmA[j]) * 0.5f;
            const float lap_u = upA[j] + umA[j] + ua[j + 2] + ua[j] - 4.0f * u;
            const float lap_v = vpA[j] + vmA[j] + va[j + 2] + va[j] - 4.0f * v;
            const float rx = (u - puA[j]) * DT_INV + u * u_x + v * u_y - NU_C * lap_u;
            const float ry = (v - pvA[j]) * DT_INV + u * v_x + v * v_y - NU_C * lap_v;
            const float dv = u_x + v_y;
            s_pde += rx * rx + ry * ry;
            s_div += dv * dv;
        }
    }

    // ---- reduction ----
#pragma unroll
    for (int off = 32; off > 0; off >>= 1) {
        s_pde += __shfl_down(s_pde, off);
        s_div += __shfl_down(s_div, off);
    }

    __syncthreads();   // all LDS stencil reads done; safe to reuse smem
    if (lane == 0) { smem[wv] = s_pde; smem[8 + wv] = s_div; }
    __syncthreads();
    if (t == 0) {
        partial[blockIdx.x]        = smem[0] + smem[1] + smem[2] + smem[3];
        partial[NBLK + blockIdx.x] = smem[8] + smem[9] + smem[10] + smem[11];
    }
}

__global__ __launch_bounds__(256) void ns_reduce(
    const float* __restrict__ partial,
    float* __restrict__ out)
{
    double sp = 0.0, sd = 0.0;
    for (int i = threadIdx.x; i < NBLK; i += 256) {
        sp += (double)partial[i];
        sd += (double)partial[NBLK + i];
    }
#pragma unroll
    for (int off = 32; off > 0; off >>= 1) {
        sp += __shfl_down(sp, off);
        sd += __shfl_down(sd, off);
    }
    __shared__ double ssp[4], ssd[4];
    const int lane = threadIdx.x & 63;
    const int wv   = threadIdx.x >> 6;
    if (lane == 0) { ssp[wv] = sp; ssd[wv] = sd; }
    __syncthreads();
    if (threadIdx.x == 0) {
        const double tp = ssp[0] + ssp[1] + ssp[2] + ssp[3];
        const double td = ssd[0] + ssd[1] + ssd[2] + ssd[3];
        const double inv = 1.0 / (double)NPTS;
        const double pde = tp * inv;
        const double dvl = td * inv;
        out[0] = (float)(pde + 0.1 * dvl);
        out[1] = (float)pde;
        out[2] = (float)dvl;
    }
}

extern "C" void kernel_launch(void* const* d_in, const int* in_sizes, int n_in,
                              void* d_out, int out_size, void* d_ws, size_t ws_size,
                              hipStream_t stream) {
    const float* u_pred = (const float*)d_in[0];
    const float* u_prev = (const float*)d_in[1];
    float* out = (float*)d_out;
    float* partial = (float*)d_ws;   // 2*NBLK floats = 16 KB

    ns_loss_v5<<<NBLK, 256, 0, stream>>>(u_pred, u_prev, partial);
    ns_reduce<<<1, 256, 0, stream>>>(partial, out);
}